// Round 4
// baseline (449.494 us; speedup 1.0000x reference)
//
#include <hip/hip_runtime.h>
#include <math.h>

#define NN 6000
#define EE 100000
#define ELL (EE + NN)   // edges + self loops for GAT

// ---------------- CSR build (dst-sorted, includes GAT self-loops) -------------
__device__ __forceinline__ int dst_of(int j, const int* __restrict__ ei){
  return (j < EE) ? ei[EE + j] : (j - EE);
}

// fused degree + per-relation count (cnt immediately follows deg in ws; one memset)
__global__ void k_degcnt(const int* __restrict__ ei, const int* __restrict__ et,
                         int* __restrict__ deg, float* __restrict__ cnt){
  int j = blockIdx.x*256 + threadIdx.x;
  if (j >= ELL) return;
  if (j < EE){
    int d = ei[EE+j]; int r = et[j];
    atomicAdd(&deg[d], 1);
    atomicAdd(&cnt[r*NN+d], 1.0f);
  } else {
    atomicAdd(&deg[j-EE], 1);
  }
}

// single-block exclusive scan over NN=6000 (256 threads x 24 elements)
__global__ void k_scan(const int* __restrict__ deg, int* __restrict__ rowptr,
                       int* __restrict__ cursor){
  __shared__ int ssum[256];
  const int PER = 24; // 256*24 = 6144 >= 6000
  int tid = threadIdx.x;
  int base = tid*PER;
  int local[PER];
  int s = 0;
  #pragma unroll
  for (int k=0;k<PER;k++){ int i = base+k; int v = (i<NN)?deg[i]:0; local[k]=s; s+=v; }
  ssum[tid] = s; __syncthreads();
  for (int off=1; off<256; off<<=1){
    int v = (tid>=off) ? ssum[tid-off] : 0;
    __syncthreads();
    ssum[tid] += v;
    __syncthreads();
  }
  int prefix = (tid==0) ? 0 : ssum[tid-1];
  #pragma unroll
  for (int k=0;k<PER;k++){
    int i = base+k;
    if (i<NN){ int v = prefix+local[k]; rowptr[i]=v; cursor[i]=v; }
  }
  if (tid==255) rowptr[NN] = ssum[255];
}

__global__ void k_fill(const int* __restrict__ ei, int* __restrict__ cursor,
                       int* __restrict__ eids){
  int j = blockIdx.x*256 + threadIdx.x;
  if (j >= ELL) return;
  int d = dst_of(j, ei);
  int pos = atomicAdd(&cursor[d], 1);
  eids[pos] = j;
}

// ---- merged weight prep: W0 [2,N,32] then Wcat (L1/L2/L3 packed, 24576) ----
__global__ void k_prep(const float* __restrict__ basis0, const float* __restrict__ comp0,
                       const float* __restrict__ b1,const float* __restrict__ c1,const float* __restrict__ r1,
                       const float* __restrict__ b2,const float* __restrict__ c2,const float* __restrict__ r2,
                       const float* __restrict__ b3,const float* __restrict__ c3,const float* __restrict__ r3,
                       float* __restrict__ W0, float* __restrict__ Wcat){
  int t0 = blockIdx.x*256 + threadIdx.x;
  if (t0 < 2*NN*32){
    int r = t0 / (NN*32);
    int no = t0 - r*(NN*32);
    float acc = 0.f;
    #pragma unroll
    for (int b=0;b<4;b++) acc += comp0[r*4+b] * basis0[b*(NN*32)+no];
    W0[t0] = acc;
    return;
  }
  int tw = t0 - 2*NN*32;
  if (tw >= 24576) return;
  const float *bb,*cc,*rr; int I,O; int t = tw;
  if (tw < 6144)        { bb=b1;cc=c1;rr=r1;I=32;O=64; }
  else if (tw < 18432)  { bb=b2;cc=c2;rr=r2;I=64;O=64; t -= 6144; }
  else                  { bb=b3;cc=c3;rr=r3;I=64;O=32; t -= 18432; }
  int C = 3*O;
  int i = t / C; int col = t - i*C;
  float v;
  if (col < O) {
    v = rr[i*O + col];
  } else {
    int r = (col - O) / O; int o = col - O - r*O;
    v = 0.f;
    #pragma unroll
    for (int b=0;b<4;b++) v += cc[r*4+b]*bb[(b*I+i)*O + o];
  }
  Wcat[tw] = v;
}

// fused layer-0 aggregation + combine + tanh (gather via CSR, skip self-loops)
__global__ void k_ragg0(const float* __restrict__ W0, const float* __restrict__ root,
                        const float* __restrict__ rbias,
                        const int* __restrict__ rowptr, const int* __restrict__ eids,
                        const int* __restrict__ ei, const int* __restrict__ et,
                        const float* __restrict__ cnt, float* __restrict__ xout){
  int n = blockIdx.x*8 + (threadIdx.x >> 5);
  int o = threadIdx.x & 31;
  if (n >= NN) return;
  int r0 = rowptr[n], r1 = rowptr[n+1];
  float a0 = 0.f, a1 = 0.f;
  for (int j=r0;j<r1;j++){
    int jj = eids[j];
    if (jj >= EE) continue;          // self-loop: GAT only
    int s = ei[jj]; int r = et[jj];
    float v = W0[(r*NN + s)*32 + o];
    if (r==0) a0 += v; else a1 += v;
  }
  float v = root[n*32+o] + rbias[o]
          + a0/fmaxf(cnt[n],1.f) + a1/fmaxf(cnt[NN+n],1.f);
  xout[n*32+o] = tanhf(v);
}

// H = x @ Wcat : [N, 3O]  (cols [0,O)=root term, [O,2O)=rel0, [2O,3O)=rel1)
__global__ void k_nodemm(const float* __restrict__ x, const float* __restrict__ Wcat,
                         float* __restrict__ H, int I, int O){
  int C = 3*O;
  int t = blockIdx.x*256 + threadIdx.x;
  if (t >= NN*C) return;
  int n = t / C; int c = t - n*C;
  float acc = 0.f;
  for (int i=0;i<I;i++) acc += x[n*I+i]*Wcat[i*C+c];
  H[t] = acc;
}

// fused RGCN agg + mean + root + tanh for layers 1..3
template<int O>
__global__ void k_ragg(const float* __restrict__ H, const float* __restrict__ rbias,
                       const int* __restrict__ rowptr, const int* __restrict__ eids,
                       const int* __restrict__ ei, const int* __restrict__ et,
                       const float* __restrict__ cnt, float* __restrict__ xout){
  constexpr int NPB = 256/O;
  int n = blockIdx.x*NPB + threadIdx.x/O;
  int o = threadIdx.x % O;
  if (n >= NN) return;
  int r0 = rowptr[n], r1 = rowptr[n+1];
  float a0 = 0.f, a1 = 0.f;
  for (int j=r0;j<r1;j++){
    int jj = eids[j];
    if (jj >= EE) continue;
    int s = ei[jj]; int r = et[jj];
    float v = H[s*3*O + O + r*O + o];
    if (r==0) a0 += v; else a1 += v;
  }
  float v = H[n*3*O + o] + rbias[o]
          + a0/fmaxf(cnt[n],1.f) + a1/fmaxf(cnt[NN+n],1.f);
  xout[n*O+o] = tanhf(v);
}

// ---- GAT: h = x@gw (8 nodes/block) fused with per-node scores ----
__global__ void k_gat(const float* __restrict__ x, const float* __restrict__ gw,
                      const float* __restrict__ as_, const float* __restrict__ ad_,
                      float* __restrict__ h, float* __restrict__ asv, float* __restrict__ adv){
  int n0 = blockIdx.x*8;
  int t = threadIdx.x;  // 128 threads: t*4 covers 512 channels
  __shared__ float sx[8*32];
  __shared__ float red[2][16];
  for (int c=t; c<8*32; c+=128) sx[c] = x[n0*32 + c];
  __syncthreads();
  float4 acc[8];
  #pragma unroll
  for (int k=0;k<8;k++) acc[k] = {0,0,0,0};
  for (int i=0;i<32;i++){
    const float4 g = *(const float4*)&gw[i*512 + t*4];
    #pragma unroll
    for (int k=0;k<8;k++){
      float xv = sx[k*32+i];
      acc[k].x += xv*g.x; acc[k].y += xv*g.y; acc[k].z += xv*g.z; acc[k].w += xv*g.w;
    }
  }
  const float4 a4 = *(const float4*)&as_[t*4];
  const float4 d4 = *(const float4*)&ad_[t*4];
  float sa[8], sd[8];
  #pragma unroll
  for (int k=0;k<8;k++){
    *(float4*)&h[(n0+k)*512 + t*4] = acc[k];
    sa[k] = acc[k].x*a4.x + acc[k].y*a4.y + acc[k].z*a4.z + acc[k].w*a4.w;
    sd[k] = acc[k].x*d4.x + acc[k].y*d4.y + acc[k].z*d4.z + acc[k].w*d4.w;
  }
  #pragma unroll
  for (int m=32;m>0;m>>=1){
    #pragma unroll
    for (int k=0;k<8;k++){ sa[k] += __shfl_xor(sa[k],m,64); sd[k] += __shfl_xor(sd[k],m,64); }
  }
  int wv = t>>6;
  if ((t&63)==0){
    #pragma unroll
    for (int k=0;k<8;k++){ red[wv][k]=sa[k]; red[wv][8+k]=sd[k]; }
  }
  __syncthreads();
  if (t<8)              asv[n0+t]   = red[0][t]+red[1][t];
  else if (t<16)        adv[n0+t-8] = red[0][t]+red[1][t];
}

// fused per-node softmax over incident edges; coef stored by CSR slot
__global__ void k_gat_soft(const int* __restrict__ rowptr, const int* __restrict__ eids,
                           const int* __restrict__ ei, const float* __restrict__ asv,
                           const float* __restrict__ adv, float* __restrict__ coef){
  int n = blockIdx.x*4 + (threadIdx.x >> 6);
  int lane = threadIdx.x & 63;
  if (n >= NN) return;
  int r0 = rowptr[n], r1 = rowptr[n+1];
  float advn = adv[n];
  float m = -1e30f;
  for (int j=r0+lane; j<r1; j+=64){
    int jj = eids[j]; int s = (jj<EE)? ei[jj] : jj-EE;
    float a = asv[s] + advn; a = (a>=0.f)? a : 0.2f*a;
    m = fmaxf(m, a);
  }
  #pragma unroll
  for (int off=32;off>0;off>>=1) m = fmaxf(m, __shfl_xor(m,off,64));
  float sum = 0.f;
  for (int j=r0+lane; j<r1; j+=64){
    int jj = eids[j]; int s = (jj<EE)? ei[jj] : jj-EE;
    float a = asv[s] + advn; a = (a>=0.f)? a : 0.2f*a;
    sum += expf(a - m);
  }
  #pragma unroll
  for (int off=32;off>0;off>>=1) sum += __shfl_xor(sum,off,64);
  float inv = 1.f / fmaxf(sum, 1e-16f);
  for (int j=r0+lane; j<r1; j+=64){
    int jj = eids[j]; int s = (jj<EE)? ei[jj] : jj-EE;
    float a = asv[s] + advn; a = (a>=0.f)? a : 0.2f*a;
    coef[j] = expf(a - m) * inv;
  }
}

// per-node gather aggregation + bias + relu
__global__ void k_gat_agg(const int* __restrict__ rowptr, const int* __restrict__ eids,
                          const int* __restrict__ ei, const float* __restrict__ coef,
                          const float* __restrict__ h, const float* __restrict__ bias,
                          float* __restrict__ gout){
  int n = blockIdx.x;
  int c = threadIdx.x;             // 128 threads * float4 = 512 channels
  int r0 = rowptr[n], r1 = rowptr[n+1];
  float4 acc = {0.f,0.f,0.f,0.f};
  for (int j=r0;j<r1;j++){
    int jj = eids[j]; int s = (jj<EE)? ei[jj] : jj-EE;
    float cf = coef[j];
    const float4 hv = *(const float4*)&h[s*512 + c*4];
    acc.x += cf*hv.x; acc.y += cf*hv.y; acc.z += cf*hv.z; acc.w += cf*hv.w;
  }
  const float4 b = *(const float4*)&bias[c*4];
  float4 o;
  o.x = fmaxf(acc.x+b.x, 0.f); o.y = fmaxf(acc.y+b.y, 0.f);
  o.z = fmaxf(acc.z+b.z, 0.f); o.w = fmaxf(acc.w+b.w, 0.f);
  *(float4*)&gout[n*512 + c*4] = o;
}

// ---- edge MLP precompute: A = x@w1[:512], B = x@w1[512:] ----
// MT=32 nodes/block to amortize w1 (L2 traffic /4); x-tile reads are
// wave-uniform LDS broadcasts; each thread owns 2 consecutive cols (float2 w).
__global__ void k_AB(const float* __restrict__ x5, const float* __restrict__ w1,
                     float* __restrict__ A, float* __restrict__ B){
  __shared__ float sx[32*512];   // 64 KB
  int n0 = blockIdx.x*32;
  {
    const float4* src = (const float4*)x5;
    float4* dst = (float4*)sx;
    int base = n0*128;                       // float4 units
    for (int c = threadIdx.x; c < 32*128; c += 256){
      int gi = base + c;
      if (gi < NN*128) dst[c] = src[gi];
    }
  }
  __syncthreads();
  int j2    = (threadIdx.x & 63)*2;        // 2 consecutive cols
  int half  = (threadIdx.x >> 6) & 1;      // 0 -> A, 1 -> B
  int tbase = (threadIdx.x >> 7) * 16;     // nodes [tbase, tbase+16)
  const float* wj = w1 + half*512*128 + j2;
  float acc[32];
  #pragma unroll
  for (int k=0;k<32;k++) acc[k] = 0.f;
  for (int c4=0;c4<128;c4++){
    const float* wc = wj + c4*4*128;
    const float2 w0 = *(const float2*)(wc);
    const float2 w1v= *(const float2*)(wc+128);
    const float2 w2v= *(const float2*)(wc+256);
    const float2 w3v= *(const float2*)(wc+384);
    #pragma unroll
    for (int tt=0;tt<16;tt++){
      const float4 xv = *(const float4*)&sx[(tbase+tt)*512 + c4*4];
      acc[tt*2]   += xv.x*w0.x + xv.y*w1v.x + xv.z*w2v.x + xv.w*w3v.x;
      acc[tt*2+1] += xv.x*w0.y + xv.y*w1v.y + xv.z*w2v.y + xv.w*w3v.y;
    }
  }
  float* dst = half ? B : A;
  #pragma unroll
  for (int tt=0;tt<16;tt++){
    int node = n0 + tbase + tt;
    if (node < NN){
      float2 o = {acc[tt*2], acc[tt*2+1]};
      *(float2*)&dst[node*128 + j2] = o;
    }
  }
}

__global__ void k_edge(const int* __restrict__ ei, const float* __restrict__ A,
                       const float* __restrict__ B, const float* __restrict__ b1,
                       const float* __restrict__ w2, const float* __restrict__ b2,
                       float* __restrict__ out){
  int e = blockIdx.x*4 + (threadIdx.x >> 6);
  int lane = threadIdx.x & 63;
  if (e >= EE) return;
  int s = ei[e], d = ei[EE+e];
  const float2 av = *(const float2*)&A[s*128 + lane*2];
  const float2 bv = *(const float2*)&B[d*128 + lane*2];
  const float2 b1v = *(const float2*)&b1[lane*2];
  const float2 w2v = *(const float2*)&w2[lane*2];
  float h0 = fmaxf(av.x + bv.x + b1v.x, 0.f);
  float h1 = fmaxf(av.y + bv.y + b1v.y, 0.f);
  float acc = h0*w2v.x + h1*w2v.y;
  #pragma unroll
  for (int m=32;m>0;m>>=1) acc += __shfl_xor(acc,m,64);
  if (lane==0) out[e] = 1.f/(1.f + expf(-(acc + b2[0])));
}

extern "C" void kernel_launch(void* const* d_in, const int* in_sizes, int n_in,
                              void* d_out, int out_size, void* d_ws, size_t ws_size,
                              hipStream_t stream){
  const float* basis0 = (const float*)d_in[0];
  const float* comp0  = (const float*)d_in[1];
  const float* root0  = (const float*)d_in[2];
  const float* rbias0 = (const float*)d_in[3];
  const float* basisL[4] = {basis0,(const float*)d_in[4],(const float*)d_in[8],(const float*)d_in[12]};
  const float* compL[4]  = {comp0,(const float*)d_in[5],(const float*)d_in[9],(const float*)d_in[13]};
  const float* rootL[4]  = {root0,(const float*)d_in[6],(const float*)d_in[10],(const float*)d_in[14]};
  const float* rbiasL[4] = {rbias0,(const float*)d_in[7],(const float*)d_in[11],(const float*)d_in[15]};
  const float* gat_w = (const float*)d_in[16];
  const float* a_src = (const float*)d_in[17];
  const float* a_dst = (const float*)d_in[18];
  const float* gat_b = (const float*)d_in[19];
  const float* w1 = (const float*)d_in[20];
  const float* b1 = (const float*)d_in[21];
  const float* w2 = (const float*)d_in[22];
  const float* b2 = (const float*)d_in[23];
  const int* ei = (const int*)d_in[24];
  const int* et = (const int*)d_in[25];
  float* out = (float*)d_out;

  // workspace carve-up (deg+cnt adjacent: one memset)
  float* p = (float*)d_ws;
  int* deg    = (int*)p; p += NN;
  float* cnt  = p; p += 2*NN;
  int* rowptr = (int*)p; p += NN+1;
  int* cursor = (int*)p; p += NN;
  int* eids   = (int*)p; p += ELL;
  float* W0   = p; p += 2*NN*32;
  float* Wcat = p; p += 24576;
  float* xa   = p; p += NN*64;
  float* xb   = p; p += NN*64;
  float* H    = p; p += NN*192;
  float* h    = p; p += NN*512;
  float* asv  = p; p += NN;
  float* adv  = p; p += NN;
  float* coef = p; p += ELL;
  float* gout = p; p += NN*512;
  float* A    = p; p += NN*128;
  float* B    = p; p += NN*128;

  auto grid = [](long long n){ return dim3((unsigned)((n + 255)/256)); };

  // ---- weight prep (independent of graph) ----
  k_prep<<<grid(2LL*NN*32 + 24576),256,0,stream>>>(basis0, comp0,
        basisL[1],compL[1],rootL[1], basisL[2],compL[2],rootL[2],
        basisL[3],compL[3],rootL[3], W0, Wcat);

  // ---- CSR build ----
  hipMemsetAsync(deg, 0, (size_t)3*NN*sizeof(int), stream);  // deg + cnt
  k_degcnt<<<grid(ELL),256,0,stream>>>(ei, et, deg, cnt);
  k_scan<<<1,256,0,stream>>>(deg, rowptr, cursor);
  k_fill<<<grid(ELL),256,0,stream>>>(ei, cursor, eids);

  // ---- RGCN layer 0 (x = I) ----
  k_ragg0<<<dim3((NN+7)/8),256,0,stream>>>(W0, root0, rbias0, rowptr, eids, ei, et, cnt, xa);

  // ---- RGCN layers 1..3 ----
  int Is[4] = {NN,32,64,64}, Os[4] = {32,64,64,32};
  int WcatOff[4] = {0, 0, 6144, 18432};
  float* xin = xa; float* xout = xb;
  for (int l=1;l<4;l++){
    int I=Is[l], O=Os[l];
    k_nodemm<<<grid((long long)NN*3*O),256,0,stream>>>(xin, Wcat + WcatOff[l], H, I, O);
    if (O == 64)
      k_ragg<64><<<dim3((NN+3)/4),256,0,stream>>>(H, rbiasL[l], rowptr, eids, ei, et, cnt, xout);
    else
      k_ragg<32><<<dim3((NN+7)/8),256,0,stream>>>(H, rbiasL[l], rowptr, eids, ei, et, cnt, xout);
    float* tmp = xin; xin = xout; xout = tmp;
  }
  // final RGCN output (N x 32) in xin

  // ---- GAT ----
  k_gat<<<dim3(NN/8),128,0,stream>>>(xin, gat_w, a_src, a_dst, h, asv, adv);
  k_gat_soft<<<dim3((NN+3)/4),256,0,stream>>>(rowptr, eids, ei, asv, adv, coef);
  k_gat_agg<<<dim3(NN),128,0,stream>>>(rowptr, eids, ei, coef, h, gat_b, gout);

  // ---- edge MLP ----
  k_AB<<<dim3((NN+31)/32),256,0,stream>>>(gout, w1, A, B);
  k_edge<<<dim3((EE+3)/4),256,0,stream>>>(ei, A, B, b1, w2, b2, out);
}